// Round 6
// baseline (412.507 us; speedup 1.0000x reference)
//
#include <hip/hip_runtime.h>
#include <hip/hip_bf16.h>
#include <cstdint>

typedef __attribute__((ext_vector_type(8))) short bf16x8;
typedef __attribute__((ext_vector_type(4))) float f32x4;
typedef __attribute__((ext_vector_type(4))) int   i32x4;
typedef __attribute__((ext_vector_type(16))) int  i32x16;

static constexpr int Mdim = 8192;
static constexpr int Kdim = 4096;
static constexpr int Ndim = 4096;
static constexpr int BM = 256, BN = 256;   // 256^2 pipelined tile (T3/T4 structure)
static constexpr int BKB = 128;            // K-bytes per tile (i8 => 128 k-elems)
static constexpr int NKT = Kdim / BKB;     // 32 K-tiles

__device__ __forceinline__ void async_copy16(const void* g, void* l) {
  __builtin_amdgcn_global_load_lds(
      (const __attribute__((address_space(1))) void*)g,
      (__attribute__((address_space(3))) void*)l, 16, 0, 0);
}

// ---- prepass 1: per-row absmax quantize x fp32 -> i8, store s_row ----
__global__ __launch_bounds__(256) void quant_x_kernel(const float* __restrict__ x,
                                                      int8_t* __restrict__ xq,
                                                      float* __restrict__ srow) {
  const int tid = threadIdx.x;
  const int row = blockIdx.x * 8 + (tid >> 5);
  const int l   = tid & 31;
  const float* xr = x + (size_t)row * Kdim;
  float4 v[32];
  float m = 0.f;
  #pragma unroll
  for (int j = 0; j < 32; ++j) {
    v[j] = *reinterpret_cast<const float4*>(xr + (size_t)(j * 32 + l) * 4);
    m = fmaxf(m, fmaxf(fmaxf(fabsf(v[j].x), fabsf(v[j].y)),
                       fmaxf(fabsf(v[j].z), fabsf(v[j].w))));
  }
  #pragma unroll
  for (int s = 16; s >= 1; s >>= 1) m = fmaxf(m, __shfl_xor(m, s, 64));
  const float rs = (m > 0.f) ? (127.0f / m) : 0.f;
  if (l == 0) srow[row] = m * (1.0f / 127.0f);
  uint32_t* xq32 = reinterpret_cast<uint32_t*>(xq + (size_t)row * Kdim);
  #pragma unroll
  for (int j = 0; j < 32; ++j) {
    int a0 = (int)rintf(v[j].x * rs), a1 = (int)rintf(v[j].y * rs);
    int a2 = (int)rintf(v[j].z * rs), a3 = (int)rintf(v[j].w * rs);
    uint32_t p = (uint32_t)(a0 & 255) | ((uint32_t)(a1 & 255) << 8) |
                 ((uint32_t)(a2 & 255) << 16) | ((uint32_t)(a3 & 255) << 24);
    xq32[j * 32 + l] = p;
  }
}

// ---- prepass 2: w [K][N] fp32 -> wsT [N][K] i8 = sign(w), LDS transpose ----
__global__ __launch_bounds__(256) void sign_w_kernel(const float* __restrict__ w,
                                                     int8_t* __restrict__ wsT) {
  __shared__ int8_t t[64 * 68];
  const int bid = blockIdx.x;
  const int k0 = (bid & 63) * 64;
  const int n0 = (bid >> 6) * 64;
  const int tid = threadIdx.x;
  #pragma unroll
  for (int r = 0; r < 4; ++r) {
    int c  = r * 256 + tid;
    int k  = c >> 4;
    int n4 = (c & 15) * 4;
    float4 v = *reinterpret_cast<const float4*>(w + (size_t)(k0 + k) * Ndim + n0 + n4);
    int s0 = (v.x > 0.f) - (v.x < 0.f);
    int s1 = (v.y > 0.f) - (v.y < 0.f);
    int s2 = (v.z > 0.f) - (v.z < 0.f);
    int s3 = (v.w > 0.f) - (v.w < 0.f);
    uint32_t p = (uint32_t)(s0 & 255) | ((uint32_t)(s1 & 255) << 8) |
                 ((uint32_t)(s2 & 255) << 16) | ((uint32_t)(s3 & 255) << 24);
    *reinterpret_cast<uint32_t*>(&t[k * 68 + n4]) = p;
  }
  __syncthreads();
  const int n  = tid & 63;
  const int ck = (tid >> 6) * 16;
  union { int8_t b[16]; uint4 u; } o;
  #pragma unroll
  for (int j = 0; j < 16; ++j) o.b[j] = t[(ck + j) * 68 + n];
  *reinterpret_cast<uint4*>(wsT + (size_t)(n0 + n) * Kdim + k0 + ck) = o.u;
}

// ---- main GEMM: i8, 32x32x32 MFMA, 256x256 tile, 8 waves, depth-2 pipeline,
//      counted vmcnt + raw barriers (no vmcnt(0) drain in steady state),
//      XOR-swizzled LDS (linear dest + pre-swizzled source + swizzled read).
//
// vmcnt ledger (verified by hand, R2):
//   prologue: stage(0)+fence+stage(1)  -> 16 in flight, tile0's 8 oldest.
//   iter t top: in flight = {tile t: 8 oldest, tile t+1: 8}.
//     vmcnt(8) retires exactly tile t's 8 (vmcnt retires in order).
//     barrier globalizes the per-wave guarantee.
//   iter t tail: barrier (all waves done reading buf b), then stage(t+2,b)
//     -> back to 16 in flight. t >= NKT-2: no stage. t == NKT-1: vmcnt(0).
// Swizzle closure: LDS slot (r, c') holds global chunk c'^(r&7); read uses
//   cx = (k ^ (row&7)); row&7 == m&7 since wm, i*32 are multiples of 8.
__global__ __launch_bounds__(512, 2) void gemm_i8_kernel(const int8_t* __restrict__ A,
                                                         const int8_t* __restrict__ Bt,
                                                         const float* __restrict__ srow,
                                                         const float* __restrict__ bias,
                                                         float* __restrict__ out) {
  __shared__ int8_t sA[2][BM * BKB];   // 2 x 32 KB
  __shared__ int8_t sB[2][BN * BKB];   // 2 x 32 KB   -> 128 KiB total, 1 block/CU
  const int tid = threadIdx.x;

  // T1: XCD-chunked bijective block swizzle (nwg = 512, 512 % 8 == 0)
  const int nwg = (Mdim / BM) * (Ndim / BN);      // 512
  const int bid = blockIdx.x;
  const int swz = (bid & 7) * (nwg >> 3) + (bid >> 3);
  const int bm  = swz / (Ndim / BN);
  const int bn  = swz % (Ndim / BN);

  const int lane = tid & 63;
  const int wave = tid >> 6;            // 0..7, arranged 2(M) x 4(N)
  const int wm   = (wave & 1) * 128;    // wave 128x64 output sub-tile origin
  const int wn   = (wave >> 1) * 64;
  const int m    = lane & 31;           // MFMA row/col index
  const int h    = lane >> 5;           // k-half selector
  const int em   = m & 7;               // swizzle key (wm, i*32 are mult of 8)

  // staging: 4 slots/thread/matrix; lane reads the pre-swizzled global chunk
  const int8_t* pA[4];
  const int8_t* pB[4];
  #pragma unroll
  for (int p = 0; p < 4; ++p) {
    int s  = tid + 512 * p;             // 2048 slots of 16 B = 32 KB
    int r  = s >> 3;                    // row 0..255
    int cg = (s & 7) ^ (r & 7);         // inverse-swizzled source chunk
    pA[p] = A  + (size_t)(bm * BM + r) * Kdim + cg * 16;
    pB[p] = Bt + (size_t)(bn * BN + r) * Kdim + cg * 16;
  }

  i32x16 acc[4][2] = {};

  auto stage = [&](int t, int b) {
    const int k0 = t * BKB;
    #pragma unroll
    for (int p = 0; p < 4; ++p) {
      async_copy16(pA[p] + k0, &sA[b][(tid + 512 * p) * 16]);
      async_copy16(pB[p] + k0, &sB[b][(tid + 512 * p) * 16]);
    }
  };

  // prologue: two K-tiles in flight (16 loads/thread).  The fence between the
  // two stages pins per-wave issue order (tile0's 8 loads strictly before
  // tile1's 8) so that vmcnt(8) == "tile0 landed".
  stage(0, 0);
  asm volatile("" ::: "memory");
  stage(1, 1);

  for (int t = 0; t < NKT; ++t) {
    const int b = t & 1;

    // wait for tile t's 8 loads (tile t+1's 8 stay in flight); barrier makes
    // the guarantee global across waves (vmcnt is per-wave).
    if (t < NKT - 1) asm volatile("s_waitcnt vmcnt(8)" ::: "memory");
    else             asm volatile("s_waitcnt vmcnt(0)" ::: "memory");
    __builtin_amdgcn_sched_barrier(0);
    __builtin_amdgcn_s_barrier();
    __builtin_amdgcn_sched_barrier(0);

    const int8_t* la = &sA[b][0];
    const int8_t* lb = &sB[b][0];
    #pragma unroll
    for (int ks = 0; ks < 4; ++ks) {
      const int cx = ((ks * 2 + h) ^ em) * 16;   // swizzled byte offset in row
      i32x4 af[4], bf[2];
      #pragma unroll
      for (int i = 0; i < 4; ++i)
        af[i] = *reinterpret_cast<const i32x4*>(&la[(wm + i * 32 + m) * BKB + cx]);
      #pragma unroll
      for (int j = 0; j < 2; ++j)
        bf[j] = *reinterpret_cast<const i32x4*>(&lb[(wn + j * 32 + m) * BKB + cx]);
      __builtin_amdgcn_s_setprio(1);
      #pragma unroll
      for (int i = 0; i < 4; ++i)
        #pragma unroll
        for (int j = 0; j < 2; ++j)
          acc[i][j] = __builtin_amdgcn_mfma_i32_32x32x32_i8(af[i], bf[j], acc[i][j], 0, 0, 0);
      __builtin_amdgcn_s_setprio(0);
    }

    // all waves done reading dbuf[b] before anyone overwrites it
    __builtin_amdgcn_sched_barrier(0);
    __builtin_amdgcn_s_barrier();
    __builtin_amdgcn_sched_barrier(0);
    if (t < NKT - 2) stage(t + 2, b);
  }

  // epilogue: C/D 32x32 layout col=lane&31, row=(reg&3)+8*(reg>>2)+4*h
  float bv[2];
  #pragma unroll
  for (int j = 0; j < 2; ++j) bv[j] = bias[bn * BN + wn + j * 32 + m];
  #pragma unroll
  for (int i = 0; i < 4; ++i) {
    const int base_row = bm * BM + wm + i * 32 + 4 * h;
    #pragma unroll
    for (int gg = 0; gg < 4; ++gg) {
      float sv[4];
      #pragma unroll
      for (int rr = 0; rr < 4; ++rr) sv[rr] = srow[base_row + gg * 8 + rr];
      #pragma unroll
      for (int j = 0; j < 2; ++j) {
        const int col = bn * BN + wn + j * 32 + m;
        #pragma unroll
        for (int rr = 0; rr < 4; ++rr) {
          const int reg = gg * 4 + rr;
          out[(size_t)(base_row + gg * 8 + rr) * Ndim + col] =
              (float)acc[i][j][reg] * sv[rr] + bv[j];
        }
      }
    }
  }
}

// ---- fallback (no workspace): fused bf16 convert/binarize staging ----
__global__ __launch_bounds__(256) void gemm_fused_kernel(const float* __restrict__ X,
                                                         const float* __restrict__ W,
                                                         const float* __restrict__ bias,
                                                         float* __restrict__ out) {
  __shared__ __hip_bfloat16 sA[128 * 32];
  __shared__ __hip_bfloat16 sB[128 * 32];
  const int tid  = threadIdx.x;
  const int bn   = blockIdx.x, bm = blockIdx.y;
  const int lane = tid & 63;
  const int wave = tid >> 6;
  const int wm   = (wave & 1) * 64;
  const int wn   = (wave >> 1) * 64;
  const int lr   = lane & 15;
  const int quad = lane >> 4;

  f32x4 acc[4][4] = {};

  for (int k0 = 0; k0 < Kdim; k0 += 32) {
    #pragma unroll
    for (int r = 0; r < 2; ++r) {
      int c = r * 256 + tid;
      int row = c >> 2, col = (c & 3) * 8;
      const float4* p = reinterpret_cast<const float4*>(X + (size_t)(bm * 128 + row) * Kdim + k0 + col);
      float4 v0 = p[0], v1 = p[1];
      float va[8] = {v0.x, v0.y, v0.z, v0.w, v1.x, v1.y, v1.z, v1.w};
      union { __hip_bfloat16 h[8]; uint4 u; } oa;
      #pragma unroll
      for (int u2 = 0; u2 < 8; ++u2) oa.h[u2] = __float2bfloat16(va[u2]);
      *reinterpret_cast<uint4*>(&sA[c * 8]) = oa.u;

      int kl = c >> 4, n8 = (c & 15) * 8;
      const float4* q = reinterpret_cast<const float4*>(W + (size_t)(k0 + kl) * Ndim + bn * 128 + n8);
      float4 w0 = q[0], w1 = q[1];
      float wv[8] = {w0.x, w0.y, w0.z, w0.w, w1.x, w1.y, w1.z, w1.w};
      #pragma unroll
      for (int u2 = 0; u2 < 8; ++u2) {
        float sg = (wv[u2] > 0.f) ? 1.f : ((wv[u2] < 0.f) ? -1.f : 0.f);
        sB[(n8 + u2) * 32 + kl] = __float2bfloat16(sg);
      }
    }
    __syncthreads();

    bf16x8 af[4], bf[4];
    #pragma unroll
    for (int i = 0; i < 4; ++i)
      af[i] = *reinterpret_cast<const bf16x8*>(&sA[(wm + i * 16 + lr) * 32 + quad * 8]);
    #pragma unroll
    for (int j = 0; j < 4; ++j)
      bf[j] = *reinterpret_cast<const bf16x8*>(&sB[(wn + j * 16 + lr) * 32 + quad * 8]);
    #pragma unroll
    for (int i = 0; i < 4; ++i)
      #pragma unroll
      for (int j = 0; j < 4; ++j)
        acc[i][j] = __builtin_amdgcn_mfma_f32_16x16x32_bf16(af[i], bf[j], acc[i][j], 0, 0, 0);
    __syncthreads();
  }

  float bv[4];
  #pragma unroll
  for (int j = 0; j < 4; ++j) bv[j] = bias[bn * 128 + wn + j * 16 + lr];
  #pragma unroll
  for (int i = 0; i < 4; ++i) {
    const size_t rowb = (size_t)(bm * 128 + wm + i * 16 + quad * 4);
    #pragma unroll
    for (int j = 0; j < 4; ++j) {
      const int col = bn * 128 + wn + j * 16 + lr;
      float* o = out + rowb * Ndim + col;
      #pragma unroll
      for (int r = 0; r < 4; ++r)
        o[(size_t)r * Ndim] = acc[i][j][r] + bv[j];
    }
  }
}

extern "C" void kernel_launch(void* const* d_in, const int* in_sizes, int n_in,
                              void* d_out, int out_size, void* d_ws, size_t ws_size,
                              hipStream_t stream) {
  const float* x = (const float*)d_in[0];   // [8192,4096]
  const float* w = (const float*)d_in[1];   // [4096,4096]
  const float* b = (const float*)d_in[2];   // [4096]
  float* out = (float*)d_out;

  const size_t xq_bytes = (size_t)Mdim * Kdim;        // 32 MiB
  const size_t wt_bytes = (size_t)Ndim * Kdim;        // 16 MiB
  const size_t sr_bytes = (size_t)Mdim * sizeof(float);
  const size_t need = xq_bytes + wt_bytes + sr_bytes;

  if (ws_size >= need) {
    int8_t* xq  = (int8_t*)d_ws;
    int8_t* wsT = (int8_t*)((char*)d_ws + xq_bytes);
    float* srow = (float*)((char*)d_ws + xq_bytes + wt_bytes);
    quant_x_kernel<<<Mdim / 8, 256, 0, stream>>>(x, xq, srow);
    sign_w_kernel<<<(Kdim / 64) * (Ndim / 64), 256, 0, stream>>>(w, wsT);
    gemm_i8_kernel<<<(Mdim / BM) * (Ndim / BN), 512, 0, stream>>>(xq, wsT, srow, b, out);
  } else {
    gemm_fused_kernel<<<dim3(Ndim / 128, Mdim / 128), 256, 0, stream>>>(x, w, b, out);
  }
}